// Round 14
// baseline (629.416 us; speedup 1.0000x reference)
//
#include <hip/hip_runtime.h>
#include <math.h>

#define NROWS 200000
#define MCOLS 256
#define KINST 200
#define NLAB  201
#define SPLIT 8        // gather blocks per label
#define HBLK  64       // histogram partial blocks
#define PP    20       // probe passes for small kernels (pass 0 real)

// ---- ws layout (float/int elements) ----
// [0,16384)        hist64 (int)
// [16384,16585)    hist | [16640,16842) off | [16896,17097) cursor(pass0 slot unused)
// [17408,217408)   rowidx (int N)
// [217408,268608)  seg (200*256)  <- zeroed by k_hist
// probe scratch:
// [268608,284992)  hist64b (int 16384)
// [284992,290112)  cursorM (int PP*256)        <- zeroed by k_hist
// [290112,490112)  rowidx2 (int N)
// [490112,490116)  outs (float 4, scratch out)

__device__ __forceinline__ float sigf(float x) {
    return __builtin_amdgcn_rcpf(1.0f + __expf(-x));
}

__global__ __launch_bounds__(256) void k_hist(const int* __restrict__ labels,
                                              int* __restrict__ hist64,
                                              int* __restrict__ hist64b,
                                              int* __restrict__ cursorM,
                                              float* __restrict__ seg,
                                              float* __restrict__ out) {
    const int gt = blockIdx.x * 256 + threadIdx.x;
    for (int e = gt; e < KINST * MCOLS; e += HBLK * 256) seg[e] = 0.0f;
    for (int e = gt; e < PP * 256; e += HBLK * 256) cursorM[e] = 0;
    if (gt < 4) out[gt] = 0.0f;

    __shared__ int lh[NLAB];
    for (int pass = 0; pass < PP; ++pass) {
        int* dst = (pass == 0) ? hist64 : hist64b;
        for (int t = threadIdx.x; t < NLAB; t += 256) lh[t] = 0;
        __syncthreads();
        for (int i = gt; i < NROWS; i += HBLK * 256)
            atomicAdd(&lh[labels[i]], 1);
        __syncthreads();
        for (int t = threadIdx.x; t < NLAB; t += 256)
            dst[t * HBLK + blockIdx.x] = lh[t];
        __syncthreads();
    }
}

__global__ __launch_bounds__(256) void k_scatter(const int* __restrict__ labels,
                                                 const int* __restrict__ hist64,
                                                 int* __restrict__ hist,
                                                 int* __restrict__ off,
                                                 int* __restrict__ cursorM,
                                                 int* __restrict__ rowidx,
                                                 int* __restrict__ rowidx2) {
    __shared__ int sc[256];
    __shared__ int s_off[NLAB + 1];
    __shared__ int lh[NLAB];
    __shared__ int lbase[NLAB];
    const int t = threadIdx.x;

    int v = 0;
    if (t < NLAB) {
        const int4* p = (const int4*)(hist64 + t * HBLK);
        #pragma unroll
        for (int q = 0; q < HBLK / 4; ++q) {
            const int4 h = p[q];
            v += h.x + h.y + h.z + h.w;
        }
    }
    sc[t] = v;
    __syncthreads();
    for (int d = 1; d < 256; d <<= 1) {
        const int add = (t >= d) ? sc[t - d] : 0;
        __syncthreads();
        sc[t] += add;
        __syncthreads();
    }
    if (t < NLAB) s_off[t] = sc[t] - v;
    if (t == NLAB - 1) s_off[NLAB] = sc[t];
    if (blockIdx.x == 0) {
        if (t < NLAB) { hist[t] = v; off[t] = sc[t] - v; }
        if (t == NLAB - 1) off[NLAB] = sc[t];
    }
    __syncthreads();

    const int chunk = (NROWS + gridDim.x - 1) / gridDim.x;
    const int lo = blockIdx.x * chunk;
    int hi = lo + chunk; if (hi > NROWS) hi = NROWS;

    for (int pass = 0; pass < PP; ++pass) {
        int* cur = cursorM + pass * 256;
        int* dst = (pass == 0) ? rowidx : rowidx2;
        for (int q = t; q < NLAB; q += 256) lh[q] = 0;
        __syncthreads();
        for (int i = lo + t; i < hi; i += 256) atomicAdd(&lh[labels[i]], 1);
        __syncthreads();
        for (int q = t; q < NLAB; q += 256) {
            const int c = lh[q];
            lbase[q] = c ? (s_off[q] + atomicAdd(&cur[q], c)) : 0;
            lh[q] = 0;
        }
        __syncthreads();
        for (int i = lo + t; i < hi; i += 256) {
            const int l = labels[i];
            dst[lbase[l] + atomicAdd(&lh[l], 1)] = i;
        }
        __syncthreads();
    }
}

__global__ __launch_bounds__(256, 8) void k_main(const float* __restrict__ x,
                                                 const int* __restrict__ rowidx,
                                                 const int* __restrict__ off,
                                                 float* __restrict__ seg,
                                                 float* __restrict__ out) {
    const int label = blockIdx.x / SPLIT;
    const int s     = blockIdx.x % SPLIT;
    const int lo = off[label], hi = off[label + 1];
    const int cnt = hi - lo;
    const int per = (cnt + SPLIT - 1) / SPLIT;
    const int a = lo + s * per;
    int b = a + per; if (b > hi) b = hi;
    const int nb = b - a;
    if (nb <= 0) return;
    const int wave = threadIdx.x >> 6, lane = threadIdx.x & 63;
    const unsigned lz = (unsigned)lane << 2;

    __shared__ int   idx[512];
    __shared__ float buf[4][256];

    const bool lds_ok = (nb <= 512);
    if (lds_ok) {
        for (int i = threadIdx.x; i < nb; i += 256) idx[i] = rowidx[a + i];
        __syncthreads();
    }
    #define ROWID(r) (lds_ok ? idx[r] : rowidx[a + (r)])
    #define XROW(rr) (const float4*)(x + (((unsigned)(rr) << 8) + lz))

    if (label == 0) {
        float acc = 0.0f;
        int r = wave;
        for (; r + 12 < nb; r += 16) {
            const int r0 = ROWID(r), r1 = ROWID(r + 4), r2 = ROWID(r + 8), r3 = ROWID(r + 12);
            const float4 u0 = *XROW(r0);
            const float4 u1 = *XROW(r1);
            const float4 u2 = *XROW(r2);
            const float4 u3 = *XROW(r3);
            acc += sigf(u0.x) + sigf(u0.y) + sigf(u0.z) + sigf(u0.w);
            acc += sigf(u1.x) + sigf(u1.y) + sigf(u1.z) + sigf(u1.w);
            acc += sigf(u2.x) + sigf(u2.y) + sigf(u2.z) + sigf(u2.w);
            acc += sigf(u3.x) + sigf(u3.y) + sigf(u3.z) + sigf(u3.w);
        }
        for (; r < nb; r += 4) {
            const int r0 = ROWID(r);
            const float4 u = *XROW(r0);
            acc += sigf(u.x) + sigf(u.y) + sigf(u.z) + sigf(u.w);
        }
        for (int o = 32; o > 0; o >>= 1) acc += __shfl_xor(acc, o);
        if (lane == 0) buf[0][wave] = acc;
        __syncthreads();
        if (threadIdx.x == 0) {
            const float c = (buf[0][0] + buf[0][1] + buf[0][2] + buf[0][3])
                            / ((float)cnt * (float)MCOLS);
            atomicAdd(&out[3], c);
            atomicAdd(&out[0], c);
        }
    } else {
        float m0 = 1.f, m1 = 1.f, m2 = 1.f, m3 = 1.f;
        float e0 = 0.f, e1 = 0.f, e2 = 0.f, e3 = 0.f;
        int r = wave;
        for (; r + 12 < nb; r += 16) {
            const int r0 = ROWID(r), r1 = ROWID(r + 4), r2 = ROWID(r + 8), r3 = ROWID(r + 12);
            const float4 u0 = *XROW(r0);
            const float4 u1 = *XROW(r1);
            const float4 u2 = *XROW(r2);
            const float4 u3 = *XROW(r3);
            m0 *= (1.0f + __expf(-u0.x)) * (1.0f + __expf(-u1.x));
            m0 *= (1.0f + __expf(-u2.x)) * (1.0f + __expf(-u3.x));
            m1 *= (1.0f + __expf(-u0.y)) * (1.0f + __expf(-u1.y));
            m1 *= (1.0f + __expf(-u2.y)) * (1.0f + __expf(-u3.y));
            m2 *= (1.0f + __expf(-u0.z)) * (1.0f + __expf(-u1.z));
            m2 *= (1.0f + __expf(-u2.z)) * (1.0f + __expf(-u3.z));
            m3 *= (1.0f + __expf(-u0.w)) * (1.0f + __expf(-u1.w));
            m3 *= (1.0f + __expf(-u2.w)) * (1.0f + __expf(-u3.w));
            int k0, k1, k2, k3;
            m0 = frexpf(m0, &k0); e0 += (float)k0;
            m1 = frexpf(m1, &k1); e1 += (float)k1;
            m2 = frexpf(m2, &k2); e2 += (float)k2;
            m3 = frexpf(m3, &k3); e3 += (float)k3;
        }
        for (; r < nb; r += 4) {
            const int r0 = ROWID(r);
            const float4 u = *XROW(r0);
            m0 *= (1.0f + __expf(-u.x));
            m1 *= (1.0f + __expf(-u.y));
            m2 *= (1.0f + __expf(-u.z));
            m3 *= (1.0f + __expf(-u.w));
        }
        const float LN2 = 0.6931471805599453f;
        buf[wave][lane * 4 + 0] = -(e0 * LN2 + __logf(m0));
        buf[wave][lane * 4 + 1] = -(e1 * LN2 + __logf(m1));
        buf[wave][lane * 4 + 2] = -(e2 * LN2 + __logf(m2));
        buf[wave][lane * 4 + 3] = -(e3 * LN2 + __logf(m3));
        __syncthreads();
        const int c = threadIdx.x;
        const float v = buf[0][c] + buf[1][c] + buf[2][c] + buf[3][c];
        atomicAdd(&seg[(size_t)(label - 1) * MCOLS + c], v);
    }
    #undef ROWID
    #undef XROW
}

__global__ __launch_bounds__(256) void k_tail(const float* __restrict__ seg,
                                              const int* __restrict__ hist,
                                              float* __restrict__ out,
                                              float* __restrict__ outs) {
    const int i = blockIdx.x;
    const int tid = threadIdx.x, wave = tid >> 6, lane = tid & 63;
    __shared__ int   s_hist[NLAB];
    __shared__ float s_red[4];
    for (int t = tid; t < NLAB; t += 256) s_hist[t] = hist[t];
    __syncthreads();
    const int cnt_i = s_hist[i + 1];
    if (cnt_i == 0) return;

    int np;
    {
        int c = 0;
        for (int q = lane; q < KINST; q += 64) c += (s_hist[q + 1] > 0) ? 1 : 0;
        for (int o = 32; o > 0; o >>= 1) c += __shfl_xor(c, o);
        np = c;
    }
    const float inv_np    = 1.0f / (float)max(np, 1);
    const long long pr    = (long long)np * (np - 1);
    const float inv_pairs = 1.0f / (float)(pr > 0 ? pr : 1);

    const float4 sgi = *(const float4*)(seg + (size_t)i * MCOLS + lane * 4);
    const float inv = 1.0f / (float)cnt_i;
    const float g0 = sgi.x * inv, g1 = sgi.y * inv, g2 = sgi.z * inv, g3 = sgi.w * inv;
    float4 pi;
    pi.x = __expf(g0); pi.y = __expf(g1); pi.z = __expf(g2); pi.w = __expf(g3);

    for (int pass = 0; pass < PP; ++pass) {
        float* o_ = (pass == 0) ? out : outs;

        if (wave == 0) {
            float m = fmaxf(fmaxf(g0, g1), fmaxf(g2, g3));
            for (int o = 32; o > 0; o >>= 1) m = fmaxf(m, __shfl_xor(m, o));
            float e = __expf(g0 - m) + __expf(g1 - m) + __expf(g2 - m) + __expf(g3 - m);
            for (int o = 32; o > 0; o >>= 1) e += __shfl_xor(e, o);
            if (lane == 0) {
                const float c = -(m + __logf(e)) * inv_np;
                atomicAdd(&o_[1], c);
                atomicAdd(&o_[0], c);
            }
        }

        float rep = 0.0f;
        for (int j = wave; j < KINST; j += 4) {
            const int cnt_j = s_hist[j + 1];
            if (j == i || cnt_j == 0) continue;
            const float4 sgj = *(const float4*)(seg + (size_t)j * MCOLS + lane * 4);
            const float invj = 1.0f / (float)cnt_j;
            const float dx = pi.x - __expf(sgj.x * invj);
            const float dy = pi.y - __expf(sgj.y * invj);
            const float dz = pi.z - __expf(sgj.z * invj);
            const float dw = pi.w - __expf(sgj.w * invj);
            float sq = dx * dx + dy * dy + dz * dz + dw * dw;
            for (int o = 32; o > 0; o >>= 1) sq += __shfl_xor(sq, o);
            if (lane == 0) rep += fmaxf(1.0f - sqrtf(sq), 0.0f);
        }
        if (lane == 0) s_red[wave] = rep;
        __syncthreads();
        if (tid == 0) {
            const float c = (s_red[0] + s_red[1] + s_red[2] + s_red[3]) * inv_pairs;
            atomicAdd(&o_[2], c);
            atomicAdd(&o_[0], c);
        }
        __syncthreads();
    }
}

extern "C" void kernel_launch(void* const* d_in, const int* in_sizes, int n_in,
                              void* d_out, int out_size, void* d_ws, size_t ws_size,
                              hipStream_t stream) {
    const float* x      = (const float*)d_in[0];
    const int*   labels = (const int*)d_in[1];
    float* out = (float*)d_out;
    float* w   = (float*)d_ws;

    int*   hist64  = (int*)w;
    int*   hist    = (int*)(w + 16384);
    int*   off     = (int*)(w + 16640);
    int*   rowidx  = (int*)(w + 17408);
    float* seg     = w + 217408;
    int*   hist64b = (int*)(w + 268608);
    int*   cursorM = (int*)(w + 284992);
    int*   rowidx2 = (int*)(w + 290112);
    float* outs    = w + 490112;

    k_hist   <<<HBLK, 256, 0, stream>>>(labels, hist64, hist64b, cursorM, seg, out);
    k_scatter<<<256, 256, 0, stream>>>(labels, hist64, hist, off, cursorM, rowidx, rowidx2);
    k_main   <<<NLAB * SPLIT, 256, 0, stream>>>(x, rowidx, off, seg, out);
    k_tail   <<<KINST, 256, 0, stream>>>(seg, hist, out, outs);
}

// Round 15
// 102.596 us; speedup vs baseline: 6.1349x; 6.1349x over previous
//
#include <hip/hip_runtime.h>
#include <math.h>

#define NROWS 200000
#define MCOLS 256
#define KINST 200
#define NLAB  201
#define SPLIT 8        // k_main: gather blocks per label
#define JSPLIT 8       // k_tail: blocks per label i (j-range split)
#define JCH   (KINST / JSPLIT)   // 25 j's per block
#define HBLK  64       // histogram partial blocks

// ---- ws layout (float/int elements) ----
// [0,16384)        hist64 (int) | [16384..] hist | [16640..] off | [16896..] cursor
// [17408,217408)   rowidx (int N)     <- k_scatter
// [217408,268608)  seg (200*256)      <- zeroed by k_hist
//
// Journal (probes R11/R14): k_main ~31.5us (latency/trans-bound, NOT HBM);
// k_tail was ~26us at 9% occupancy (200 blocks, latency-exposed j-loop) -> R15
// splits j over JSPLIT=8 blocks/label. k_hist+k_scatter ~2.3us combined.
// ~8us/dispatch fixed overhead. __threadfence ~9us (R8/R9) - banned.

__device__ __forceinline__ float sigf(float x) {
    return __builtin_amdgcn_rcpf(1.0f + __expf(-x));
}

__global__ __launch_bounds__(256) void k_hist(const int* __restrict__ labels,
                                              int* __restrict__ hist64,
                                              int* __restrict__ cursor,
                                              float* __restrict__ seg,
                                              float* __restrict__ out) {
    const int gt = blockIdx.x * 256 + threadIdx.x;
    for (int e = gt; e < KINST * MCOLS; e += HBLK * 256) seg[e] = 0.0f;
    if (gt < NLAB) cursor[gt] = 0;
    if (gt < 4) out[gt] = 0.0f;     // out rebuilt by atomics each call

    __shared__ int lh[NLAB];
    for (int t = threadIdx.x; t < NLAB; t += 256) lh[t] = 0;
    __syncthreads();
    for (int i = gt; i < NROWS; i += HBLK * 256)
        atomicAdd(&lh[labels[i]], 1);
    __syncthreads();
    for (int t = threadIdx.x; t < NLAB; t += 256)
        hist64[t * HBLK + blockIdx.x] = lh[t];
}

__global__ __launch_bounds__(256) void k_scatter(const int* __restrict__ labels,
                                                 const int* __restrict__ hist64,
                                                 int* __restrict__ hist,
                                                 int* __restrict__ off,
                                                 int* __restrict__ cursor,
                                                 int* __restrict__ rowidx) {
    __shared__ int sc[256];
    __shared__ int s_off[NLAB + 1];
    __shared__ int lh[NLAB];
    __shared__ int lbase[NLAB];
    const int t = threadIdx.x;

    int v = 0;
    if (t < NLAB) {
        const int4* p = (const int4*)(hist64 + t * HBLK);
        #pragma unroll
        for (int q = 0; q < HBLK / 4; ++q) {
            const int4 h = p[q];
            v += h.x + h.y + h.z + h.w;
        }
    }
    sc[t] = v;
    __syncthreads();
    for (int d = 1; d < 256; d <<= 1) {
        const int add = (t >= d) ? sc[t - d] : 0;
        __syncthreads();
        sc[t] += add;
        __syncthreads();
    }
    if (t < NLAB) s_off[t] = sc[t] - v;
    if (t == NLAB - 1) s_off[NLAB] = sc[t];
    if (blockIdx.x == 0) {
        if (t < NLAB) { hist[t] = v; off[t] = sc[t] - v; }
        if (t == NLAB - 1) off[NLAB] = sc[t];
    }
    for (int q = t; q < NLAB; q += 256) lh[q] = 0;
    __syncthreads();

    const int chunk = (NROWS + gridDim.x - 1) / gridDim.x;
    const int lo = blockIdx.x * chunk;
    int hi = lo + chunk; if (hi > NROWS) hi = NROWS;
    for (int i = lo + t; i < hi; i += 256) atomicAdd(&lh[labels[i]], 1);
    __syncthreads();
    for (int q = t; q < NLAB; q += 256) {
        const int c = lh[q];
        lbase[q] = c ? (s_off[q] + atomicAdd(&cursor[q], c)) : 0;
        lh[q] = 0;
    }
    __syncthreads();
    for (int i = lo + t; i < hi; i += 256) {
        const int l = labels[i];
        rowidx[lbase[l] + atomicAdd(&lh[l], 1)] = i;
    }
}

// Hot kernel: gather rows of one label; log->product accumulation (R12).
__global__ __launch_bounds__(256, 8) void k_main(const float* __restrict__ x,
                                                 const int* __restrict__ rowidx,
                                                 const int* __restrict__ off,
                                                 float* __restrict__ seg,
                                                 float* __restrict__ out) {
    const int label = blockIdx.x / SPLIT;
    const int s     = blockIdx.x % SPLIT;
    const int lo = off[label], hi = off[label + 1];
    const int cnt = hi - lo;
    const int per = (cnt + SPLIT - 1) / SPLIT;
    const int a = lo + s * per;
    int b = a + per; if (b > hi) b = hi;
    const int nb = b - a;
    if (nb <= 0) return;
    const int wave = threadIdx.x >> 6, lane = threadIdx.x & 63;
    const unsigned lz = (unsigned)lane << 2;

    __shared__ int   idx[512];
    __shared__ float buf[4][256];

    const bool lds_ok = (nb <= 512);
    if (lds_ok) {
        for (int i = threadIdx.x; i < nb; i += 256) idx[i] = rowidx[a + i];
        __syncthreads();
    }
    #define ROWID(r) (lds_ok ? idx[r] : rowidx[a + (r)])
    #define XROW(rr) (const float4*)(x + (((unsigned)(rr) << 8) + lz))

    if (label == 0) {
        float acc = 0.0f;
        int r = wave;
        for (; r + 12 < nb; r += 16) {
            const int r0 = ROWID(r), r1 = ROWID(r + 4), r2 = ROWID(r + 8), r3 = ROWID(r + 12);
            const float4 u0 = *XROW(r0);
            const float4 u1 = *XROW(r1);
            const float4 u2 = *XROW(r2);
            const float4 u3 = *XROW(r3);
            acc += sigf(u0.x) + sigf(u0.y) + sigf(u0.z) + sigf(u0.w);
            acc += sigf(u1.x) + sigf(u1.y) + sigf(u1.z) + sigf(u1.w);
            acc += sigf(u2.x) + sigf(u2.y) + sigf(u2.z) + sigf(u2.w);
            acc += sigf(u3.x) + sigf(u3.y) + sigf(u3.z) + sigf(u3.w);
        }
        for (; r < nb; r += 4) {
            const int r0 = ROWID(r);
            const float4 u = *XROW(r0);
            acc += sigf(u.x) + sigf(u.y) + sigf(u.z) + sigf(u.w);
        }
        for (int o = 32; o > 0; o >>= 1) acc += __shfl_xor(acc, o);
        if (lane == 0) buf[0][wave] = acc;
        __syncthreads();
        if (threadIdx.x == 0) {
            const float c = (buf[0][0] + buf[0][1] + buf[0][2] + buf[0][3])
                            / ((float)cnt * (float)MCOLS);
            atomicAdd(&out[3], c);
            atomicAdd(&out[0], c);
        }
    } else {
        float m0 = 1.f, m1 = 1.f, m2 = 1.f, m3 = 1.f;
        float e0 = 0.f, e1 = 0.f, e2 = 0.f, e3 = 0.f;
        int r = wave;
        for (; r + 12 < nb; r += 16) {
            const int r0 = ROWID(r), r1 = ROWID(r + 4), r2 = ROWID(r + 8), r3 = ROWID(r + 12);
            const float4 u0 = *XROW(r0);
            const float4 u1 = *XROW(r1);
            const float4 u2 = *XROW(r2);
            const float4 u3 = *XROW(r3);
            m0 *= (1.0f + __expf(-u0.x)) * (1.0f + __expf(-u1.x));
            m0 *= (1.0f + __expf(-u2.x)) * (1.0f + __expf(-u3.x));
            m1 *= (1.0f + __expf(-u0.y)) * (1.0f + __expf(-u1.y));
            m1 *= (1.0f + __expf(-u2.y)) * (1.0f + __expf(-u3.y));
            m2 *= (1.0f + __expf(-u0.z)) * (1.0f + __expf(-u1.z));
            m2 *= (1.0f + __expf(-u2.z)) * (1.0f + __expf(-u3.z));
            m3 *= (1.0f + __expf(-u0.w)) * (1.0f + __expf(-u1.w));
            m3 *= (1.0f + __expf(-u2.w)) * (1.0f + __expf(-u3.w));
            int k0, k1, k2, k3;
            m0 = frexpf(m0, &k0); e0 += (float)k0;
            m1 = frexpf(m1, &k1); e1 += (float)k1;
            m2 = frexpf(m2, &k2); e2 += (float)k2;
            m3 = frexpf(m3, &k3); e3 += (float)k3;
        }
        for (; r < nb; r += 4) {
            const int r0 = ROWID(r);
            const float4 u = *XROW(r0);
            m0 *= (1.0f + __expf(-u.x));
            m1 *= (1.0f + __expf(-u.y));
            m2 *= (1.0f + __expf(-u.z));
            m3 *= (1.0f + __expf(-u.w));
        }
        const float LN2 = 0.6931471805599453f;
        buf[wave][lane * 4 + 0] = -(e0 * LN2 + __logf(m0));
        buf[wave][lane * 4 + 1] = -(e1 * LN2 + __logf(m1));
        buf[wave][lane * 4 + 2] = -(e2 * LN2 + __logf(m2));
        buf[wave][lane * 4 + 3] = -(e3 * LN2 + __logf(m3));
        __syncthreads();
        const int c = threadIdx.x;
        const float v = buf[0][c] + buf[1][c] + buf[2][c] + buf[3][c];
        atomicAdd(&seg[(size_t)(label - 1) * MCOLS + c], v);
    }
    #undef ROWID
    #undef XROW
}

// R15: grid = KINST * JSPLIT. Block (i, s): rep for j in [s*JCH, (s+1)*JCH);
// s==0 block also does the attractive LSE. Pre-scaled atomics into out[].
__global__ __launch_bounds__(256) void k_tail(const float* __restrict__ seg,
                                              const int* __restrict__ hist,
                                              float* __restrict__ out) {
    const int i = blockIdx.x / JSPLIT;
    const int s = blockIdx.x % JSPLIT;
    const int tid = threadIdx.x, wave = tid >> 6, lane = tid & 63;
    __shared__ int   s_hist[NLAB];
    __shared__ float s_red[4];
    for (int t = tid; t < NLAB; t += 256) s_hist[t] = hist[t];
    __syncthreads();
    const int cnt_i = s_hist[i + 1];
    if (cnt_i == 0) return;

    // local np / n_pairs (identical in every block)
    int np;
    {
        int c = 0;
        for (int q = lane; q < KINST; q += 64) c += (s_hist[q + 1] > 0) ? 1 : 0;
        for (int o = 32; o > 0; o >>= 1) c += __shfl_xor(c, o);
        np = c;
    }
    const float inv_np    = 1.0f / (float)max(np, 1);
    const long long pr    = (long long)np * (np - 1);
    const float inv_pairs = 1.0f / (float)(pr > 0 ? pr : 1);

    const float4 sgi = *(const float4*)(seg + (size_t)i * MCOLS + lane * 4);
    const float inv = 1.0f / (float)cnt_i;
    const float g0 = sgi.x * inv, g1 = sgi.y * inv, g2 = sgi.z * inv, g3 = sgi.w * inv;
    float4 pi;
    pi.x = __expf(g0); pi.y = __expf(g1); pi.z = __expf(g2); pi.w = __expf(g3);

    if (s == 0 && wave == 0) {   // attractive: logsumexp over 256 log_gm values
        float m = fmaxf(fmaxf(g0, g1), fmaxf(g2, g3));
        for (int o = 32; o > 0; o >>= 1) m = fmaxf(m, __shfl_xor(m, o));
        float e = __expf(g0 - m) + __expf(g1 - m) + __expf(g2 - m) + __expf(g3 - m);
        for (int o = 32; o > 0; o >>= 1) e += __shfl_xor(e, o);
        if (lane == 0) {
            const float c = -(m + __logf(e)) * inv_np;
            atomicAdd(&out[1], c);
            atomicAdd(&out[0], c);
        }
    }

    // repulsive: this block covers j in [s*JCH, s*JCH+JCH), waves stride
    float rep = 0.0f;
    const int jlo = s * JCH, jhi = jlo + JCH;
    for (int j = jlo + wave; j < jhi; j += 4) {
        const int cnt_j = s_hist[j + 1];
        if (j == i || cnt_j == 0) continue;
        const float4 sgj = *(const float4*)(seg + (size_t)j * MCOLS + lane * 4);
        const float invj = 1.0f / (float)cnt_j;
        const float dx = pi.x - __expf(sgj.x * invj);
        const float dy = pi.y - __expf(sgj.y * invj);
        const float dz = pi.z - __expf(sgj.z * invj);
        const float dw = pi.w - __expf(sgj.w * invj);
        float sq = dx * dx + dy * dy + dz * dz + dw * dw;
        for (int o = 32; o > 0; o >>= 1) sq += __shfl_xor(sq, o);
        if (lane == 0) rep += fmaxf(1.0f - sqrtf(sq), 0.0f);
    }
    if (lane == 0) s_red[wave] = rep;
    __syncthreads();
    if (tid == 0) {
        const float c = (s_red[0] + s_red[1] + s_red[2] + s_red[3]) * inv_pairs;
        if (c != 0.0f) {
            atomicAdd(&out[2], c);
            atomicAdd(&out[0], c);
        }
    }
}

extern "C" void kernel_launch(void* const* d_in, const int* in_sizes, int n_in,
                              void* d_out, int out_size, void* d_ws, size_t ws_size,
                              hipStream_t stream) {
    const float* x      = (const float*)d_in[0];
    const int*   labels = (const int*)d_in[1];
    float* out = (float*)d_out;
    float* w   = (float*)d_ws;

    int*   hist64  = (int*)w;
    int*   hist    = (int*)(w + 16384);
    int*   off     = (int*)(w + 16640);
    int*   cursor  = (int*)(w + 16896);
    int*   rowidx  = (int*)(w + 17408);
    float* seg     = w + 217408;

    k_hist   <<<HBLK, 256, 0, stream>>>(labels, hist64, cursor, seg, out);
    k_scatter<<<256, 256, 0, stream>>>(labels, hist64, hist, off, cursor, rowidx);
    k_main   <<<NLAB * SPLIT, 256, 0, stream>>>(x, rowidx, off, seg, out);
    k_tail   <<<KINST * JSPLIT, 256, 0, stream>>>(seg, hist, out);
}

// Round 16
// 70.560 us; speedup vs baseline: 8.9203x; 1.4540x over previous
//
#include <hip/hip_runtime.h>
#include <math.h>

#define NROWS 200000
#define MCOLS 256
#define KINST 200
#define NLAB  201
#define SPLIT 8        // k_main: gather blocks per label
#define HBLK  64       // histogram partial blocks

// ---- ws layout (float/int elements) ----
// [0,16384)        hist64 (int) | [16384..] hist | [16640..] off | [16896..] cursor
// [17408,217408)   rowidx (int N)     <- k_scatter
// [217408,268608)  seg (200*256)      <- zeroed by k_hist
//
// Journal: R11/R14 probes: k_main ~31.5us (trans/latency, NOT HBM); k_tail ~26us
// at 800 waves (latency-exposed j-loop); hist+scatter ~2.3us. R15: JSPLIT=8
// regressed +11.6us (8x per-block overhead + 3600 same-address device atomics
// -> cross-XCD serialization). R16: widen k_tail to 1024 thr (16 waves/block),
// same 200 blocks, same atomic count. __threadfence banned (R8/R9, ~9us).

__device__ __forceinline__ float sigf(float x) {
    return __builtin_amdgcn_rcpf(1.0f + __expf(-x));
}

__global__ __launch_bounds__(256) void k_hist(const int* __restrict__ labels,
                                              int* __restrict__ hist64,
                                              int* __restrict__ cursor,
                                              float* __restrict__ seg,
                                              float* __restrict__ out) {
    const int gt = blockIdx.x * 256 + threadIdx.x;
    for (int e = gt; e < KINST * MCOLS; e += HBLK * 256) seg[e] = 0.0f;
    if (gt < NLAB) cursor[gt] = 0;
    if (gt < 4) out[gt] = 0.0f;     // out rebuilt by atomics each call

    __shared__ int lh[NLAB];
    for (int t = threadIdx.x; t < NLAB; t += 256) lh[t] = 0;
    __syncthreads();
    for (int i = gt; i < NROWS; i += HBLK * 256)
        atomicAdd(&lh[labels[i]], 1);
    __syncthreads();
    for (int t = threadIdx.x; t < NLAB; t += 256)
        hist64[t * HBLK + blockIdx.x] = lh[t];
}

__global__ __launch_bounds__(256) void k_scatter(const int* __restrict__ labels,
                                                 const int* __restrict__ hist64,
                                                 int* __restrict__ hist,
                                                 int* __restrict__ off,
                                                 int* __restrict__ cursor,
                                                 int* __restrict__ rowidx) {
    __shared__ int sc[256];
    __shared__ int s_off[NLAB + 1];
    __shared__ int lh[NLAB];
    __shared__ int lbase[NLAB];
    const int t = threadIdx.x;

    int v = 0;
    if (t < NLAB) {
        const int4* p = (const int4*)(hist64 + t * HBLK);
        #pragma unroll
        for (int q = 0; q < HBLK / 4; ++q) {
            const int4 h = p[q];
            v += h.x + h.y + h.z + h.w;
        }
    }
    sc[t] = v;
    __syncthreads();
    for (int d = 1; d < 256; d <<= 1) {
        const int add = (t >= d) ? sc[t - d] : 0;
        __syncthreads();
        sc[t] += add;
        __syncthreads();
    }
    if (t < NLAB) s_off[t] = sc[t] - v;
    if (t == NLAB - 1) s_off[NLAB] = sc[t];
    if (blockIdx.x == 0) {
        if (t < NLAB) { hist[t] = v; off[t] = sc[t] - v; }
        if (t == NLAB - 1) off[NLAB] = sc[t];
    }
    for (int q = t; q < NLAB; q += 256) lh[q] = 0;
    __syncthreads();

    const int chunk = (NROWS + gridDim.x - 1) / gridDim.x;
    const int lo = blockIdx.x * chunk;
    int hi = lo + chunk; if (hi > NROWS) hi = NROWS;
    for (int i = lo + t; i < hi; i += 256) atomicAdd(&lh[labels[i]], 1);
    __syncthreads();
    for (int q = t; q < NLAB; q += 256) {
        const int c = lh[q];
        lbase[q] = c ? (s_off[q] + atomicAdd(&cursor[q], c)) : 0;
        lh[q] = 0;
    }
    __syncthreads();
    for (int i = lo + t; i < hi; i += 256) {
        const int l = labels[i];
        rowidx[lbase[l] + atomicAdd(&lh[l], 1)] = i;
    }
}

// Hot kernel: gather rows of one label; log->product accumulation (R12).
__global__ __launch_bounds__(256, 8) void k_main(const float* __restrict__ x,
                                                 const int* __restrict__ rowidx,
                                                 const int* __restrict__ off,
                                                 float* __restrict__ seg,
                                                 float* __restrict__ out) {
    const int label = blockIdx.x / SPLIT;
    const int s     = blockIdx.x % SPLIT;
    const int lo = off[label], hi = off[label + 1];
    const int cnt = hi - lo;
    const int per = (cnt + SPLIT - 1) / SPLIT;
    const int a = lo + s * per;
    int b = a + per; if (b > hi) b = hi;
    const int nb = b - a;
    if (nb <= 0) return;
    const int wave = threadIdx.x >> 6, lane = threadIdx.x & 63;
    const unsigned lz = (unsigned)lane << 2;

    __shared__ int   idx[512];
    __shared__ float buf[4][256];

    const bool lds_ok = (nb <= 512);
    if (lds_ok) {
        for (int i = threadIdx.x; i < nb; i += 256) idx[i] = rowidx[a + i];
        __syncthreads();
    }
    #define ROWID(r) (lds_ok ? idx[r] : rowidx[a + (r)])
    #define XROW(rr) (const float4*)(x + (((unsigned)(rr) << 8) + lz))

    if (label == 0) {
        float acc = 0.0f;
        int r = wave;
        for (; r + 12 < nb; r += 16) {
            const int r0 = ROWID(r), r1 = ROWID(r + 4), r2 = ROWID(r + 8), r3 = ROWID(r + 12);
            const float4 u0 = *XROW(r0);
            const float4 u1 = *XROW(r1);
            const float4 u2 = *XROW(r2);
            const float4 u3 = *XROW(r3);
            acc += sigf(u0.x) + sigf(u0.y) + sigf(u0.z) + sigf(u0.w);
            acc += sigf(u1.x) + sigf(u1.y) + sigf(u1.z) + sigf(u1.w);
            acc += sigf(u2.x) + sigf(u2.y) + sigf(u2.z) + sigf(u2.w);
            acc += sigf(u3.x) + sigf(u3.y) + sigf(u3.z) + sigf(u3.w);
        }
        for (; r < nb; r += 4) {
            const int r0 = ROWID(r);
            const float4 u = *XROW(r0);
            acc += sigf(u.x) + sigf(u.y) + sigf(u.z) + sigf(u.w);
        }
        for (int o = 32; o > 0; o >>= 1) acc += __shfl_xor(acc, o);
        if (lane == 0) buf[0][wave] = acc;
        __syncthreads();
        if (threadIdx.x == 0) {
            const float c = (buf[0][0] + buf[0][1] + buf[0][2] + buf[0][3])
                            / ((float)cnt * (float)MCOLS);
            atomicAdd(&out[3], c);
            atomicAdd(&out[0], c);
        }
    } else {
        float m0 = 1.f, m1 = 1.f, m2 = 1.f, m3 = 1.f;
        float e0 = 0.f, e1 = 0.f, e2 = 0.f, e3 = 0.f;
        int r = wave;
        for (; r + 12 < nb; r += 16) {
            const int r0 = ROWID(r), r1 = ROWID(r + 4), r2 = ROWID(r + 8), r3 = ROWID(r + 12);
            const float4 u0 = *XROW(r0);
            const float4 u1 = *XROW(r1);
            const float4 u2 = *XROW(r2);
            const float4 u3 = *XROW(r3);
            m0 *= (1.0f + __expf(-u0.x)) * (1.0f + __expf(-u1.x));
            m0 *= (1.0f + __expf(-u2.x)) * (1.0f + __expf(-u3.x));
            m1 *= (1.0f + __expf(-u0.y)) * (1.0f + __expf(-u1.y));
            m1 *= (1.0f + __expf(-u2.y)) * (1.0f + __expf(-u3.y));
            m2 *= (1.0f + __expf(-u0.z)) * (1.0f + __expf(-u1.z));
            m2 *= (1.0f + __expf(-u2.z)) * (1.0f + __expf(-u3.z));
            m3 *= (1.0f + __expf(-u0.w)) * (1.0f + __expf(-u1.w));
            m3 *= (1.0f + __expf(-u2.w)) * (1.0f + __expf(-u3.w));
            int k0, k1, k2, k3;
            m0 = frexpf(m0, &k0); e0 += (float)k0;
            m1 = frexpf(m1, &k1); e1 += (float)k1;
            m2 = frexpf(m2, &k2); e2 += (float)k2;
            m3 = frexpf(m3, &k3); e3 += (float)k3;
        }
        for (; r < nb; r += 4) {
            const int r0 = ROWID(r);
            const float4 u = *XROW(r0);
            m0 *= (1.0f + __expf(-u.x));
            m1 *= (1.0f + __expf(-u.y));
            m2 *= (1.0f + __expf(-u.z));
            m3 *= (1.0f + __expf(-u.w));
        }
        const float LN2 = 0.6931471805599453f;
        buf[wave][lane * 4 + 0] = -(e0 * LN2 + __logf(m0));
        buf[wave][lane * 4 + 1] = -(e1 * LN2 + __logf(m1));
        buf[wave][lane * 4 + 2] = -(e2 * LN2 + __logf(m2));
        buf[wave][lane * 4 + 3] = -(e3 * LN2 + __logf(m3));
        __syncthreads();
        const int c = threadIdx.x;
        const float v = buf[0][c] + buf[1][c] + buf[2][c] + buf[3][c];
        atomicAdd(&seg[(size_t)(label - 1) * MCOLS + c], v);
    }
    #undef ROWID
    #undef XROW
}

// R16: 200 blocks x 1024 threads (16 waves). Same work/atomics as R13; the
// extra waves hide the j-loop's load->exp->reduce latency chain.
__global__ __launch_bounds__(1024) void k_tail(const float* __restrict__ seg,
                                               const int* __restrict__ hist,
                                               float* __restrict__ out) {
    const int i = blockIdx.x;
    const int tid = threadIdx.x, wave = tid >> 6, lane = tid & 63;
    __shared__ int   s_hist[NLAB];
    __shared__ float s_red[16];
    for (int t = tid; t < NLAB; t += 1024) s_hist[t] = hist[t];
    __syncthreads();
    const int cnt_i = s_hist[i + 1];
    if (cnt_i == 0) return;

    // local np / n_pairs (identical in every block)
    int np;
    {
        int c = 0;
        for (int q = lane; q < KINST; q += 64) c += (s_hist[q + 1] > 0) ? 1 : 0;
        for (int o = 32; o > 0; o >>= 1) c += __shfl_xor(c, o);
        np = c;
    }
    const float inv_np    = 1.0f / (float)max(np, 1);
    const long long pr    = (long long)np * (np - 1);
    const float inv_pairs = 1.0f / (float)(pr > 0 ? pr : 1);

    const float4 sgi = *(const float4*)(seg + (size_t)i * MCOLS + lane * 4);
    const float inv = 1.0f / (float)cnt_i;
    const float g0 = sgi.x * inv, g1 = sgi.y * inv, g2 = sgi.z * inv, g3 = sgi.w * inv;
    float4 pi;
    pi.x = __expf(g0); pi.y = __expf(g1); pi.z = __expf(g2); pi.w = __expf(g3);

    if (wave == 0) {   // attractive: logsumexp over 256 log_gm values
        float m = fmaxf(fmaxf(g0, g1), fmaxf(g2, g3));
        for (int o = 32; o > 0; o >>= 1) m = fmaxf(m, __shfl_xor(m, o));
        float e = __expf(g0 - m) + __expf(g1 - m) + __expf(g2 - m) + __expf(g3 - m);
        for (int o = 32; o > 0; o >>= 1) e += __shfl_xor(e, o);
        if (lane == 0) {
            const float c = -(m + __logf(e)) * inv_np;
            atomicAdd(&out[1], c);
            atomicAdd(&out[0], c);
        }
    }

    // repulsive: 16 waves stride j (12-13 each)
    float rep = 0.0f;
    for (int j = wave; j < KINST; j += 16) {
        const int cnt_j = s_hist[j + 1];
        if (j == i || cnt_j == 0) continue;
        const float4 sgj = *(const float4*)(seg + (size_t)j * MCOLS + lane * 4);
        const float invj = 1.0f / (float)cnt_j;
        const float dx = pi.x - __expf(sgj.x * invj);
        const float dy = pi.y - __expf(sgj.y * invj);
        const float dz = pi.z - __expf(sgj.z * invj);
        const float dw = pi.w - __expf(sgj.w * invj);
        float sq = dx * dx + dy * dy + dz * dz + dw * dw;
        for (int o = 32; o > 0; o >>= 1) sq += __shfl_xor(sq, o);
        if (lane == 0) rep += fmaxf(1.0f - sqrtf(sq), 0.0f);
    }
    if (lane == 0) s_red[wave] = rep;
    __syncthreads();
    if (tid == 0) {
        float r = 0.0f;
        #pragma unroll
        for (int q = 0; q < 16; ++q) r += s_red[q];
        const float c = r * inv_pairs;
        atomicAdd(&out[2], c);
        atomicAdd(&out[0], c);
    }
}

extern "C" void kernel_launch(void* const* d_in, const int* in_sizes, int n_in,
                              void* d_out, int out_size, void* d_ws, size_t ws_size,
                              hipStream_t stream) {
    const float* x      = (const float*)d_in[0];
    const int*   labels = (const int*)d_in[1];
    float* out = (float*)d_out;
    float* w   = (float*)d_ws;

    int*   hist64  = (int*)w;
    int*   hist    = (int*)(w + 16384);
    int*   off     = (int*)(w + 16640);
    int*   cursor  = (int*)(w + 16896);
    int*   rowidx  = (int*)(w + 17408);
    float* seg     = w + 217408;

    k_hist   <<<HBLK, 256, 0, stream>>>(labels, hist64, cursor, seg, out);
    k_scatter<<<256, 256, 0, stream>>>(labels, hist64, hist, off, cursor, rowidx);
    k_main   <<<NLAB * SPLIT, 256, 0, stream>>>(x, rowidx, off, seg, out);
    k_tail   <<<KINST, 1024, 0, stream>>>(seg, hist, out);
}